// Round 1
// baseline (427.806 us; speedup 1.0000x reference)
//
#include <hip/hip_runtime.h>

using u16 = unsigned short;
using u32 = unsigned int;
using short8 = __attribute__((ext_vector_type(8))) short;
using short4v = __attribute__((ext_vector_type(4))) short;
using bf16x8 = __attribute__((ext_vector_type(8))) __bf16;
using f32x4 = __attribute__((ext_vector_type(4))) float;

#define ALPHA_INV (1.0f / (128.0f * 100.0f))

__device__ __forceinline__ u32 swz(u32 off, u32 row) { return off ^ ((row & 7u) << 4); }

__device__ __forceinline__ u16 f2bf(float x) {
  u32 u = __float_as_uint(x);
  u32 r = u + 0x7fffu + ((u >> 16) & 1u);
  return (u16)(r >> 16);
}

__device__ __forceinline__ f32x4 mfma(bf16x8 a, bf16x8 b, f32x4 c) {
  return __builtin_amdgcn_mfma_f32_16x16x32_bf16(a, b, c, 0, 0, 0);
}

// ---------------------------------------------------------------------------
// Weight transpose + bf16 convert: w[tap][cin][256] fp32 -> wt[tap][256][cin] bf16
// ---------------------------------------------------------------------------
__global__ void wtrans(const float* __restrict__ w, u16* __restrict__ o, int rows, int cin) {
  int idx = blockIdx.x * 256 + threadIdx.x;
  if (idx >= rows * 256) return;
  int row = idx >> 8, n = idx & 255;
  int tap = row / cin, c = row - tap * cin;
  o[((size_t)tap * 256 + n) * cin + c] = f2bf(w[idx]);
}

// batch fp32 -> bf16 (S), 4 elems/thread
__global__ void cvt_bf16_kernel(const float* __restrict__ in, u16* __restrict__ out) {
  int i = blockIdx.x * 256 + threadIdx.x;
  float4 v = ((const float4*)in)[i];
  short4v o;
  o[0] = (short)f2bf(v.x); o[1] = (short)f2bf(v.y);
  o[2] = (short)f2bf(v.z); o[3] = (short)f2bf(v.w);
  *(short4v*)(out + (size_t)i * 4) = o;
}

// ---------------------------------------------------------------------------
// Causal dilated conv as GEMM: rows = B*T (aligned to batch: T=2048 % 128 == 0)
// in: bf16 [B*T][CIN], wt: bf16 [TAPS][256][CIN] (transposed), out: bf16 [B*T][256]
// y[t] = sum_tap in[t - (TAPS-1-tap)*DIL] * w[tap]  (+bias, relu / softmax)
// ---------------------------------------------------------------------------
template <int CIN, int DIL, int TAPS, bool RELU, bool SOFTMAX>
__global__ __launch_bounds__(512) void conv_kernel(
    const u16* __restrict__ in, const u16* __restrict__ wt,
    const float* __restrict__ bias, u16* __restrict__ out) {
  constexpr int BM = 128, BN = 256, BK = 64;
  __shared__ alignas(16) u16 Al[BM * BK];
  __shared__ alignas(16) u16 Bl[BN * BK];
  __shared__ float redA[4][BM];
  __shared__ float redB[4][BM];

  const int tid = threadIdx.x;
  const int wid = tid >> 6, lane = tid & 63;
  const int wr = wid >> 2, wc = wid & 3;
  const int lg = lane >> 4, lq = lane & 15;
  const int row0 = blockIdx.x * BM;
  const int tloc0 = row0 & 2047;

  f32x4 acc[4][4];
#pragma unroll
  for (int i = 0; i < 4; ++i)
#pragma unroll
    for (int j = 0; j < 4; ++j) acc[i][j] = (f32x4)0.0f;

#pragma unroll
  for (int tap = 0; tap < TAPS; ++tap) {
    const int shift = (TAPS - 1 - tap) * DIL;
#pragma unroll
    for (int kc = 0; kc < CIN / BK; ++kc) {
      // stage A tile [128][64] (swizzled)
#pragma unroll
      for (int it = 0; it < 2; ++it) {
        int s = tid + it * 512;
        int r = s >> 3, cb = s & 7;
        short8 v = (short8)0;
        if (tloc0 + r >= shift)
          v = *(const short8*)(in + (size_t)(row0 + r - shift) * CIN + kc * BK + cb * 8);
        *(short8*)((char*)Al + swz(r * 128 + cb * 16, r)) = v;
      }
      // stage B tile [256][64] (swizzled)
#pragma unroll
      for (int it = 0; it < 4; ++it) {
        int s = tid + it * 512;
        int n = s >> 3, cb = s & 7;
        *(short8*)((char*)Bl + swz(n * 128 + cb * 16, n)) =
            *(const short8*)(wt + ((size_t)tap * BN + n) * CIN + kc * BK + cb * 8);
      }
      __syncthreads();
#pragma unroll
      for (int ks = 0; ks < 2; ++ks) {
        bf16x8 af[4], bfr[4];
#pragma unroll
        for (int mi = 0; mi < 4; ++mi) {
          int r = wr * 64 + mi * 16 + lq;
          af[mi] = *(const bf16x8*)((const char*)Al + swz(r * 128 + ks * 64 + lg * 16, r));
        }
#pragma unroll
        for (int ni = 0; ni < 4; ++ni) {
          int n = wc * 64 + ni * 16 + lq;
          bfr[ni] = *(const bf16x8*)((const char*)Bl + swz(n * 128 + ks * 64 + lg * 16, n));
        }
#pragma unroll
        for (int mi = 0; mi < 4; ++mi)
#pragma unroll
          for (int ni = 0; ni < 4; ++ni)
            acc[mi][ni] = mfma(af[mi], bfr[ni], acc[mi][ni]);
      }
      __syncthreads();
    }
  }

  float bcol[4];
#pragma unroll
  for (int ni = 0; ni < 4; ++ni) bcol[ni] = bias[wc * 64 + ni * 16 + lq];
#pragma unroll
  for (int mi = 0; mi < 4; ++mi)
#pragma unroll
    for (int ni = 0; ni < 4; ++ni)
#pragma unroll
      for (int rr = 0; rr < 4; ++rr) acc[mi][ni][rr] += bcol[ni];

  if constexpr (!SOFTMAX) {
#pragma unroll
    for (int mi = 0; mi < 4; ++mi)
#pragma unroll
      for (int ni = 0; ni < 4; ++ni)
#pragma unroll
        for (int rr = 0; rr < 4; ++rr) {
          float v = acc[mi][ni][rr];
          if (RELU) v = fmaxf(v, 0.0f);
          int row = row0 + wr * 64 + mi * 16 + lg * 4 + rr;
          int col = wc * 64 + ni * 16 + lq;
          out[(size_t)row * BN + col] = f2bf(v);
        }
  } else {
    // fused softmax over the full 256 columns (TAU = 1)
    float tmx[4][4];
#pragma unroll
    for (int mi = 0; mi < 4; ++mi)
#pragma unroll
      for (int rr = 0; rr < 4; ++rr) {
        float v = fmaxf(fmaxf(acc[mi][0][rr], acc[mi][1][rr]),
                        fmaxf(acc[mi][2][rr], acc[mi][3][rr]));
#pragma unroll
        for (int off = 1; off < 16; off <<= 1) v = fmaxf(v, __shfl_xor(v, off));
        if (lq == 0) redA[wc][wr * 64 + mi * 16 + lg * 4 + rr] = v;
      }
    __syncthreads();
#pragma unroll
    for (int mi = 0; mi < 4; ++mi)
#pragma unroll
      for (int rr = 0; rr < 4; ++rr) {
        int rb = wr * 64 + mi * 16 + lg * 4 + rr;
        tmx[mi][rr] = fmaxf(fmaxf(redA[0][rb], redA[1][rb]),
                            fmaxf(redA[2][rb], redA[3][rb]));
      }
#pragma unroll
    for (int mi = 0; mi < 4; ++mi)
#pragma unroll
      for (int rr = 0; rr < 4; ++rr) {
        float s = 0.0f;
#pragma unroll
        for (int ni = 0; ni < 4; ++ni) {
          float p = __expf(acc[mi][ni][rr] - tmx[mi][rr]);
          acc[mi][ni][rr] = p;
          s += p;
        }
#pragma unroll
        for (int off = 1; off < 16; off <<= 1) s += __shfl_xor(s, off);
        if (lq == 0) redB[wc][wr * 64 + mi * 16 + lg * 4 + rr] = s;
      }
    __syncthreads();
#pragma unroll
    for (int mi = 0; mi < 4; ++mi)
#pragma unroll
      for (int rr = 0; rr < 4; ++rr) {
        int rb = wr * 64 + mi * 16 + lg * 4 + rr;
        float inv = 1.0f / (redB[0][rb] + redB[1][rb] + redB[2][rb] + redB[3][rb]);
        int row = row0 + rb;
#pragma unroll
        for (int ni = 0; ni < 4; ++ni) {
          int col = wc * 64 + ni * 16 + lq;
          out[(size_t)row * BN + col] = f2bf(acc[mi][ni][rr] * inv);
        }
      }
  }
}

// ---------------------------------------------------------------------------
// Strict-causal linear attention:
// num[t,d] = ALPHA_INV + sum_{t'<t} (h_t . h_{t'}) * s_{t'}[d];  prob = num / rowsum
// Per block: one (b, 128-row q-tile); k-tiles of 64.
// ---------------------------------------------------------------------------
__global__ __launch_bounds__(512) void attn_kernel(
    const u16* __restrict__ H, const u16* __restrict__ S, float* __restrict__ out) {
  constexpr int TQ = 128, TK = 64, M = 256, D = 128, T = 2048;
  __shared__ alignas(16) u16 Hq[TQ * M];        // 64KB  [q][m] swizzled
  __shared__ alignas(16) u16 Hk[TK * M];        // 32KB  [k'][m] swizzled
  __shared__ alignas(16) u16 St[D * TK];        // 16KB  [d][t'] swizzled (transposed S)
  __shared__ alignas(16) u16 Pl[8][16 * TK];    // 16KB  per-wave P [q16][t'64]

  const int tid = threadIdx.x;
  const int wid = tid >> 6, lane = tid & 63;
  const int lg = lane >> 4, lq = lane & 15;
  const int b = blockIdx.y;
  const int qt = (int)gridDim.x - 1 - (int)blockIdx.x;  // heavy tiles first
  const int t0 = qt * TQ;
  const size_t hb = (size_t)b * T * M;
  const size_t sb = (size_t)b * T * D;

#pragma unroll
  for (int it = 0; it < 8; ++it) {
    int s = tid + it * 512;
    int r = s >> 5, cb = s & 31;
    *(short8*)((char*)Hq + swz(r * 512 + cb * 16, r)) =
        *(const short8*)(H + hb + (size_t)(t0 + r) * M + cb * 8);
  }

  f32x4 accO[8];
#pragma unroll
  for (int di = 0; di < 8; ++di) accO[di] = (f32x4)(ALPHA_INV);

  const int nkt = t0 / TK + 2;
  for (int kt = 0; kt < nkt; ++kt) {
    const int k0 = kt * TK;
#pragma unroll
    for (int it = 0; it < 4; ++it) {
      int s = tid + it * 512;
      int r = s >> 5, cb = s & 31;
      *(short8*)((char*)Hk + swz(r * 512 + cb * 16, r)) =
          *(const short8*)(H + hb + (size_t)(k0 + r) * M + cb * 8);
    }
#pragma unroll
    for (int it = 0; it < 2; ++it) {
      int s = tid + it * 512;
      int tt = s >> 4, db = s & 15;
      short8 v = *(const short8*)(S + sb + (size_t)(k0 + tt) * D + db * 8);
#pragma unroll
      for (int j = 0; j < 8; ++j) {
        int d = db * 8 + j;
        *(u16*)((char*)St + swz(d * 128 + tt * 2, d)) = (u16)v[j];
      }
    }
    __syncthreads();

    // GEMM1: P[16 x 64] = Hq(wave rows) @ Hk^T, K = 256
    f32x4 accP[4];
#pragma unroll
    for (int ci = 0; ci < 4; ++ci) accP[ci] = (f32x4)0.0f;
    const int rq = wid * 16 + lq;
#pragma unroll
    for (int ks = 0; ks < 8; ++ks) {
      bf16x8 a = *(const bf16x8*)((const char*)Hq + swz(rq * 512 + ks * 64 + lg * 16, rq));
#pragma unroll
      for (int ci = 0; ci < 4; ++ci) {
        int rk = ci * 16 + lq;
        bf16x8 bb = *(const bf16x8*)((const char*)Hk + swz(rk * 512 + ks * 64 + lg * 16, rk));
        accP[ci] = mfma(a, bb, accP[ci]);
      }
    }
    // strict causal mask + write P (bf16) to per-wave LDS
    const bool needmask = (k0 + TK > t0);
#pragma unroll
    for (int ci = 0; ci < 4; ++ci)
#pragma unroll
      for (int rr = 0; rr < 4; ++rr) {
        int qrow = lg * 4 + rr;
        float v = accP[ci][rr];
        if (needmask) {
          int gq = t0 + wid * 16 + qrow;
          int gk = k0 + ci * 16 + lq;
          if (gk >= gq) v = 0.0f;
        }
        *(u16*)((char*)Pl[wid] + swz(qrow * 128 + (ci * 16 + lq) * 2, qrow)) = f2bf(v);
      }
    // GEMM2: accO[16 x 128] += P @ S_k, K = 64
#pragma unroll
    for (int ks = 0; ks < 2; ++ks) {
      bf16x8 a = *(const bf16x8*)((const char*)Pl[wid] + swz(lq * 128 + ks * 64 + lg * 16, lq));
#pragma unroll
      for (int di = 0; di < 8; ++di) {
        int rd = di * 16 + lq;
        bf16x8 bb = *(const bf16x8*)((const char*)St + swz(rd * 128 + ks * 64 + lg * 16, rd));
        accO[di] = mfma(a, bb, accO[di]);
      }
    }
    __syncthreads();
  }

  // normalize rows, store fp32 probs
#pragma unroll
  for (int rr = 0; rr < 4; ++rr) {
    float s = 0.0f;
#pragma unroll
    for (int di = 0; di < 8; ++di) s += accO[di][rr];
#pragma unroll
    for (int off = 1; off < 16; off <<= 1) s += __shfl_xor(s, off);
    float inv = 1.0f / s;
    int row = t0 + wid * 16 + lg * 4 + rr;
#pragma unroll
    for (int di = 0; di < 8; ++di)
      out[sb + (size_t)row * D + di * 16 + lq] = accO[di][rr] * inv;
  }
}

// ---------------------------------------------------------------------------
// W_final split-K partials: part[b][ks][m][d] = sum_{t in slice} h[t][m] s[t][d]
// ---------------------------------------------------------------------------
__global__ __launch_bounds__(512) void wfinal_partial(
    const u16* __restrict__ H, const u16* __restrict__ S, float* __restrict__ part) {
  constexpr int M = 256, D = 128, T = 2048;
  __shared__ alignas(16) u16 Hl[64 * M];    // [t][m] 32KB
  __shared__ alignas(16) u16 Stl[D * 64];   // [d][t] 16KB
  const int tid = threadIdx.x;
  const int wid = tid >> 6, lane = tid & 63;
  const int wr = wid >> 1, wc = wid & 1;
  const int lg = lane >> 4, lq = lane & 15;
  const int ks = blockIdx.x, b = blockIdx.y;

  f32x4 acc[4][4];
#pragma unroll
  for (int i = 0; i < 4; ++i)
#pragma unroll
    for (int j = 0; j < 4; ++j) acc[i][j] = (f32x4)0.0f;

  for (int kt = 0; kt < 4; ++kt) {
    const int t00 = ks * 256 + kt * 64;
#pragma unroll
    for (int it = 0; it < 4; ++it) {
      int s = tid + it * 512;
      int r = s >> 5, cb = s & 31;
      *(short8*)((char*)Hl + swz(r * 512 + cb * 16, r)) =
          *(const short8*)(H + ((size_t)b * T + t00 + r) * M + cb * 8);
    }
#pragma unroll
    for (int it = 0; it < 2; ++it) {
      int s = tid + it * 512;
      int tt = s >> 4, db = s & 15;
      short8 v = *(const short8*)(S + ((size_t)b * T + t00 + tt) * D + db * 8);
#pragma unroll
      for (int j = 0; j < 8; ++j) {
        int d = db * 8 + j;
        *(u16*)((char*)Stl + swz(d * 128 + tt * 2, d)) = (u16)v[j];
      }
    }
    __syncthreads();
#pragma unroll
    for (int k2 = 0; k2 < 2; ++k2) {
      bf16x8 af[4];
#pragma unroll
      for (int mi = 0; mi < 4; ++mi) {
        int m = wr * 64 + mi * 16 + lq;
        short8 a;
#pragma unroll
        for (int j = 0; j < 8; ++j) {
          int t = k2 * 32 + lg * 8 + j;
          a[j] = (short)*(const u16*)((const char*)Hl + swz(t * 512 + m * 2, t));
        }
        af[mi] = __builtin_bit_cast(bf16x8, a);
      }
#pragma unroll
      for (int di = 0; di < 4; ++di) {
        int d = wc * 64 + di * 16 + lq;
        bf16x8 bb = *(const bf16x8*)((const char*)Stl + swz(d * 128 + k2 * 64 + lg * 16, d));
#pragma unroll
        for (int mi = 0; mi < 4; ++mi) acc[mi][di] = mfma(af[mi], bb, acc[mi][di]);
      }
    }
    __syncthreads();
  }
  float* dst = part + ((size_t)b * 8 + ks) * M * D;
#pragma unroll
  for (int mi = 0; mi < 4; ++mi)
#pragma unroll
    for (int di = 0; di < 4; ++di)
#pragma unroll
      for (int rr = 0; rr < 4; ++rr) {
        int m = wr * 64 + mi * 16 + lg * 4 + rr;
        int d = wc * 64 + di * 16 + lq;
        dst[(size_t)m * D + d] = acc[mi][di][rr];
      }
}

__global__ void wreduce(const float* __restrict__ part, float* __restrict__ outw) {
  int idx = blockIdx.x * 256 + threadIdx.x;  // 32*256*128 = 1048576
  int b = idx >> 15;
  int rem = idx & 32767;
  float s = ALPHA_INV;
#pragma unroll
  for (int ks = 0; ks < 8; ++ks) s += part[(((size_t)b * 8 + ks) << 15) + rem];
  outw[idx] = s;
}

// ---------------------------------------------------------------------------
extern "C" void kernel_launch(void* const* d_in, const int* in_sizes, int n_in,
                              void* d_out, int out_size, void* d_ws, size_t ws_size,
                              hipStream_t stream) {
  const float* batch = (const float*)d_in[0];
  const float* w0 = (const float*)d_in[1];
  const float* b0 = (const float*)d_in[2];
  const float* w1 = (const float*)d_in[3];
  const float* b1 = (const float*)d_in[4];
  const float* w2 = (const float*)d_in[5];
  const float* b2 = (const float*)d_in[6];
  const float* wo = (const float*)d_in[7];
  const float* bo = (const float*)d_in[8];

  // workspace layout (bytes)
  const size_t SZ_S = 16777216;     // S bf16 [B*T][128]
  const size_t SZ_BUF = 33554432;   // bf16 [B*T][256]
  const size_t NEED = SZ_S + 2 * SZ_BUF + 786432;
  if (ws_size < NEED) return;

  char* ws = (char*)d_ws;
  u16* S = (u16*)ws;
  u16* bufA = (u16*)(ws + SZ_S);
  u16* bufB = (u16*)(ws + SZ_S + SZ_BUF);
  u16* Wt0 = (u16*)(ws + SZ_S + 2 * SZ_BUF);
  u16* Wt1 = Wt0 + 2 * 256 * 128;
  u16* Wt2 = Wt1 + 2 * 256 * 256;
  u16* Wt3 = Wt2 + 2 * 256 * 256;
  float* wpart = (float*)bufA;  // reused after conv_out (h2 dead by then)
  float* probs = (float*)d_out;
  float* wfin = probs + (size_t)32 * 2048 * 128;

  wtrans<<<256, 256, 0, stream>>>(w0, Wt0, 2 * 128, 128);
  wtrans<<<512, 256, 0, stream>>>(w1, Wt1, 2 * 256, 256);
  wtrans<<<512, 256, 0, stream>>>(w2, Wt2, 2 * 256, 256);
  wtrans<<<256, 256, 0, stream>>>(wo, Wt3, 1 * 256, 256);
  cvt_bf16_kernel<<<8192, 256, 0, stream>>>(batch, S);

  conv_kernel<128, 1, 2, true, false><<<512, 512, 0, stream>>>(S, Wt0, b0, bufA);
  conv_kernel<256, 2, 2, true, false><<<512, 512, 0, stream>>>(bufA, Wt1, b1, bufB);
  conv_kernel<256, 4, 2, true, false><<<512, 512, 0, stream>>>(bufB, Wt2, b2, bufA);
  conv_kernel<256, 1, 1, false, true><<<512, 512, 0, stream>>>(bufA, Wt3, bo, bufB);

  wfinal_partial<<<dim3(8, 32), 512, 0, stream>>>(bufB, S, wpart);
  attn_kernel<<<dim3(16, 32), 512, 0, stream>>>(bufB, S, probs);
  wreduce<<<4096, 256, 0, stream>>>(wpart, wfin);
}